// Round 5
// baseline (483.988 us; speedup 1.0000x reference)
//
#include <hip/hip_runtime.h>
#include <hip/hip_bf16.h>
#include <math.h>

#define HW   4096
#define CCH  256
#define NE   8
#define HID  512
#define NTOK 65536
#define MAXT 160   // max 128-token tiles per expert (expect ~128)

typedef short s16x8 __attribute__((ext_vector_type(8)));
typedef float f32x4 __attribute__((ext_vector_type(4)));

// ---------------- K transpose+cast: in (E,R,CC) fp32 -> out (E,CC,R) bf16 ----
__global__ __launch_bounds__(256) void k_transpose_cast(
    const float* __restrict__ in, __hip_bfloat16* __restrict__ out, int R, int CC)
{
    __shared__ float t[64][65];
    int tilesC = CC >> 6;
    int per = (R >> 6) * tilesC;
    int e = blockIdx.x / per, tt = blockIdx.x % per;
    int r0 = (tt / tilesC) << 6, c0 = (tt % tilesC) << 6;
    const float* ip = in + (size_t)e * R * CC;
    __hip_bfloat16* op = out + (size_t)e * R * CC;
    int lane = threadIdx.x & 63, g = threadIdx.x >> 6;
    for (int i = 0; i < 16; i++) {
        int r = i * 4 + g;
        t[r][lane] = ip[(size_t)(r0 + r) * CC + c0 + lane];
    }
    __syncthreads();
    for (int i = 0; i < 16; i++) {
        int r = i * 4 + g;
        op[(size_t)(c0 + r) * R + r0 + lane] = __float2bfloat16(t[lane][r]);
    }
}

// ---------------- K0: x transpose -> tokens bf16, fp32 router, top2 ---------
__global__ __launch_bounds__(256) void k_router(
    const float* __restrict__ x, const float* __restrict__ Wr, const float* __restrict__ br,
    __hip_bfloat16* __restrict__ tokens, int* __restrict__ pair, float2* __restrict__ wts,
    int* __restrict__ meta /* counts at [0..8) */)
{
    __shared__ float xt[CCH][65];
    __shared__ float wr[CCH][NE];
    __shared__ float lg[64][NE];
    __shared__ int lc[NE];
    int tid = threadIdx.x;
    int n0 = blockIdx.x * 64;
    int b = n0 >> 12, p0 = n0 & 4095;
    const float* xb = x + (size_t)b * CCH * HW + p0;
    for (int i = tid; i < CCH * NE; i += 256) ((float*)wr)[i] = Wr[i];
    if (tid < NE) lc[tid] = 0;
    int lane = tid & 63, wv = tid >> 6;
    for (int i = 0; i < 64; i++) {
        int c = i * 4 + wv;
        xt[c][lane] = xb[(size_t)c * HW + lane];
    }
    __syncthreads();
    float a0 = br[2 * wv], a1 = br[2 * wv + 1];
    for (int c = 0; c < CCH; c++) {
        float xv = xt[c][lane];
        a0 = fmaf(xv, wr[c][2 * wv], a0);
        a1 = fmaf(xv, wr[c][2 * wv + 1], a1);
    }
    lg[lane][2 * wv] = a0;
    lg[lane][2 * wv + 1] = a1;
    __syncthreads();
    if (wv == 0) {
        float v0 = -1e30f, v1 = -1e30f; int i0 = 0, i1 = 0;
        for (int e = 0; e < NE; e++) {
            float l = lg[lane][e];
            if (l > v0)      { v1 = v0; i1 = i0; v0 = l; i0 = e; }
            else if (l > v1) { v1 = l; i1 = e; }
        }
        float e1 = expf(v1 - v0);
        float s = 1.0f + e1;
        wts[n0 + lane] = make_float2(1.0f / s, e1 / s);
        pair[n0 + lane] = i0 | (i1 << 8);
        atomicAdd(&lc[i0], 1);
        atomicAdd(&lc[i1], 1);
    }
    __syncthreads();
    if (tid < NE && lc[tid] > 0) atomicAdd(&meta[tid], lc[tid]);
    for (int r = 0; r < 64; r++)
        tokens[(size_t)(n0 + r) * CCH + tid] = __float2bfloat16(xt[tid][r]);
}

// ---------------- K1: scan counts -> offsets ---------------------------------
// meta: [0..8) counts, [8..16) cursors, [16..25) offsets
__global__ void k_scan(int* meta)
{
    if (threadIdx.x == 0) {
        int off = 0;
        for (int e = 0; e < NE; e++) {
            meta[16 + e] = off;
            off += meta[e];
        }
        meta[24] = off;
    }
}

// ---------------- K2: scatter tokens into per-expert lists ------------------
__global__ __launch_bounds__(256) void k_scatter(
    const int* __restrict__ pair, const float2* __restrict__ wts,
    int* __restrict__ meta, int* __restrict__ assign_tok, float* __restrict__ assign_w,
    int2* __restrict__ tok_slots)
{
    __shared__ int lcount[NE];
    __shared__ int lbase[NE];
    int tid = threadIdx.x;
    int n = blockIdx.x * 256 + tid;
    if (tid < NE) lcount[tid] = 0;
    __syncthreads();
    int pr = pair[n];
    int e0 = pr & 0xff, e1 = (pr >> 8) & 0xff;
    int p0 = atomicAdd(&lcount[e0], 1);
    int p1 = atomicAdd(&lcount[e1], 1);
    __syncthreads();
    if (tid < NE) lbase[tid] = atomicAdd(&meta[8 + tid], lcount[tid]);
    __syncthreads();
    float2 w = wts[n];
    int s0 = meta[16 + e0] + lbase[e0] + p0;
    int s1 = meta[16 + e1] + lbase[e1] + p1;
    assign_tok[s0] = n; assign_w[s0] = w.x;
    assign_tok[s1] = n; assign_w[s1] = w.y;
    tok_slots[n] = make_int2(s0, s1);
}

// ---------------- K3: grouped fused MLP (hot kernel) ------------------------
// 512 threads = 8 waves; 128-token tile; hidden in 8 chunks of 64.
// All LDS buffers are frag-linear (16B unit = one MFMA fragment slice):
//   Ab : u = k8*128 + row   (k8 = K/8 in [0,32), row in [0,128))     64 KB
//   W1b: u = k8*64  + col   (k8 in [0,32), col = hidden-in-chunk)    32 KB
//   W2b: u = k8*256 + n     (k8 = chunk-K/8 in [0,8), n = out chan)  32 KB
//   Hb : u = k8*128 + row   (k8 in [0,8))                            16 KB
// Per chunk: phase A = GEMM1 (wave 32x32, 2x2 frags) + GELU->Hb + ds_write of
// register-prefetched W2[c]; barrier; phase B = GEMM2 (wave 64x64, 4x4 frags,
// oacc 64 AGPR) + prefetch/ds_write W1[c+1]; barrier. Weight global loads are
// issued at phase top and consumed at phase end -> latency hidden by MFMAs.
__global__ __launch_bounds__(512, 2) void k_expert(
    const __hip_bfloat16* __restrict__ tokens,
    const __hip_bfloat16* __restrict__ w1t,   // (E, HID, C)  = W1^T per expert
    const __hip_bfloat16* __restrict__ w2t,   // (E, C, HID)  = W2^T per expert
    const float* __restrict__ b1, const float* __restrict__ b2,
    const int* __restrict__ meta,
    const int* __restrict__ assign_tok, const float* __restrict__ assign_w,
    __hip_bfloat16* __restrict__ ybuf)
{
    __shared__ __align__(16) char Ab[65536];
    __shared__ __align__(16) char W1b[32768];
    __shared__ __align__(16) char W2b[32768];
    __shared__ __align__(16) char Hb[16384];

    int bid = blockIdx.x;
    int e = bid & 7, t = bid >> 3;
    int cnt = meta[e];
    int tiles = (cnt + 127) >> 7;
    if (t >= tiles) return;
    int abase = meta[16 + e] + (t << 7);
    int nrows = cnt - (t << 7); if (nrows > 128) nrows = 128;

    int tid = threadIdx.x;
    int lane = tid & 63, wv = tid >> 6;
    int quad = lane >> 4, l15 = lane & 15;

    const __hip_bfloat16* w1e = w1t + (size_t)e * HID * CCH;
    const __hip_bfloat16* w2e = w2t + (size_t)e * CCH * HID;
    const float* b1e = b1 + (size_t)e * HID;

    // ---- stage A tile (gather 128 token rows, frag-linear)
    {
        int r = ((wv & 1) << 6) | lane;      // this thread's row
        int q = wv >> 1;                      // k8 phase
        int tok = (r < nrows) ? assign_tok[abase + r] : assign_tok[abase];
        const uint4* src = (const uint4*)(tokens + (size_t)tok * CCH);
        uint4 v[8];
#pragma unroll
        for (int i = 0; i < 8; i++) v[i] = src[i * 4 + q];
        uint4* dst = (uint4*)Ab;
#pragma unroll
        for (int i = 0; i < 8; i++) dst[(i * 4 + q) * 128 + r] = v[i];
    }
    // ---- stage W1 chunk 0
    {
        uint4 v[4];
#pragma unroll
        for (int i = 0; i < 4; i++)
            v[i] = *(const uint4*)(w1e + (size_t)lane * CCH + (i * 8 + wv) * 8);
        uint4* dst = (uint4*)W1b;
#pragma unroll
        for (int i = 0; i < 4; i++) dst[i * 512 + wv * 64 + lane] = v[i];
    }

    int m4 = wv & 3, n2 = wv >> 2;   // GEMM1 wave grid (4M x 2N, 32x32 tiles)
    int mh = wv & 1, nq = wv >> 1;   // GEMM2 wave grid (2M x 4N, 64x64 tiles)

    f32x4 oacc[4][4];
#pragma unroll
    for (int i = 0; i < 4; i++)
#pragma unroll
        for (int j = 0; j < 4; j++) oacc[i][j] = (f32x4){0.f, 0.f, 0.f, 0.f};

    __syncthreads();

    for (int c = 0; c < 8; c++) {
        // ---- phase A: prefetch W2[c] (consumed by ds_write at phase end)
        uint4 w2pf[4];
        {
            int n = ((wv & 3) << 6) | lane;
#pragma unroll
            for (int i = 0; i < 4; i++) {
                int k8 = i * 2 + (wv >> 2);
                w2pf[i] = *(const uint4*)(w2e + (size_t)n * HID + c * 64 + k8 * 8);
            }
        }
        // ---- GEMM1: 32x32 wave tile over K=256
        f32x4 hacc[2][2];
#pragma unroll
        for (int i = 0; i < 2; i++)
#pragma unroll
            for (int j = 0; j < 2; j++) hacc[i][j] = (f32x4){0.f, 0.f, 0.f, 0.f};
#pragma unroll
        for (int ks = 0; ks < 8; ks++) {
            s16x8 af[2], bf[2];
#pragma unroll
            for (int mf = 0; mf < 2; mf++)
                af[mf] = *(const s16x8*)(Ab + (size_t)((ks * 4 + quad) * 128 + m4 * 32 + mf * 16 + l15) * 16);
#pragma unroll
            for (int nf = 0; nf < 2; nf++)
                bf[nf] = *(const s16x8*)(W1b + (size_t)((ks * 4 + quad) * 64 + n2 * 32 + nf * 16 + l15) * 16);
#pragma unroll
            for (int mf = 0; mf < 2; mf++)
#pragma unroll
                for (int nf = 0; nf < 2; nf++)
                    hacc[mf][nf] = __builtin_amdgcn_mfma_f32_16x16x32_bf16(af[mf], bf[nf], hacc[mf][nf], 0, 0, 0);
        }
        // ---- bias + exact GELU -> Hb (frag-linear scatter)
#pragma unroll
        for (int nf = 0; nf < 2; nf++) {
            int col = n2 * 32 + nf * 16 + l15;
            float bias = b1e[c * 64 + col];
            char* hcol = Hb + (size_t)((col >> 3) * 128) * 16 + (col & 7) * 2;
#pragma unroll
            for (int mf = 0; mf < 2; mf++)
#pragma unroll
                for (int r = 0; r < 4; r++) {
                    int row = m4 * 32 + mf * 16 + quad * 4 + r;
                    float v = hacc[mf][nf][r] + bias;
                    float g = 0.5f * v * (1.0f + erff(v * 0.70710678118654752f));
                    *(__hip_bfloat16*)(hcol + (size_t)row * 16) = __float2bfloat16(g);
                }
        }
        // ---- commit W2[c] staging
        {
            int n = ((wv & 3) << 6) | lane;
            uint4* dst = (uint4*)W2b;
#pragma unroll
            for (int i = 0; i < 4; i++) {
                int k8 = i * 2 + (wv >> 2);
                dst[k8 * 256 + n] = w2pf[i];
            }
        }
        __syncthreads();

        // ---- phase B: prefetch W1[c+1]
        uint4 w1pf[4];
        if (c < 7) {
#pragma unroll
            for (int i = 0; i < 4; i++)
                w1pf[i] = *(const uint4*)(w1e + (size_t)((c + 1) * 64 + lane) * CCH + (i * 8 + wv) * 8);
        }
        // ---- GEMM2: 64x64 wave tile, K=64 chunk
#pragma unroll
        for (int ks = 0; ks < 2; ks++) {
            s16x8 hf[4], wf[4];
#pragma unroll
            for (int mt = 0; mt < 4; mt++)
                hf[mt] = *(const s16x8*)(Hb + (size_t)((ks * 4 + quad) * 128 + mh * 64 + mt * 16 + l15) * 16);
#pragma unroll
            for (int nf = 0; nf < 4; nf++)
                wf[nf] = *(const s16x8*)(W2b + (size_t)((ks * 4 + quad) * 256 + nq * 64 + nf * 16 + l15) * 16);
#pragma unroll
            for (int mt = 0; mt < 4; mt++)
#pragma unroll
                for (int nf = 0; nf < 4; nf++)
                    oacc[mt][nf] = __builtin_amdgcn_mfma_f32_16x16x32_bf16(hf[mt], wf[nf], oacc[mt][nf], 0, 0, 0);
        }
        // ---- commit W1[c+1] staging
        if (c < 7) {
            uint4* dst = (uint4*)W1b;
#pragma unroll
            for (int i = 0; i < 4; i++) dst[i * 512 + wv * 64 + lane] = w1pf[i];
            __syncthreads();
        }
    }

    // ---- epilogue: (oacc + b2) * route_weight -> ybuf[slot][col] bf16
    const float* b2e = b2 + (size_t)e * CCH;
#pragma unroll
    for (int nf = 0; nf < 4; nf++) {
        int col = nq * 64 + nf * 16 + l15;
        float bias = b2e[col];
#pragma unroll
        for (int mt = 0; mt < 4; mt++) {
#pragma unroll
            for (int r = 0; r < 4; r++) {
                int row = mh * 64 + mt * 16 + quad * 4 + r;
                if (row < nrows) {
                    float w = assign_w[abase + row];
                    float v = (oacc[mt][nf][r] + bias) * w;
                    ybuf[(size_t)(abase + row) * CCH + col] = __float2bfloat16(v);
                }
            }
        }
    }
}

// ---------------- K4: combine two expert outputs, transpose back, residual --
__global__ __launch_bounds__(256) void k_combine(
    const float* __restrict__ x, const __hip_bfloat16* __restrict__ ybuf,
    const int2* __restrict__ tok_slots, const float* __restrict__ scale,
    float* __restrict__ out)
{
    __shared__ float moe[CCH][65];
    __shared__ int2 slots[64];
    int tid = threadIdx.x;
    int n0 = blockIdx.x * 64;
    if (tid < 64) slots[tid] = tok_slots[n0 + tid];
    __syncthreads();
    for (int r = 0; r < 64; r++) {
        int2 s = slots[r];
        float y = __bfloat162float(ybuf[(size_t)s.x * CCH + tid]) +
                  __bfloat162float(ybuf[(size_t)s.y * CCH + tid]);
        moe[tid][r] = y;
    }
    __syncthreads();
    float sc = scale[0];
    int b = n0 >> 12, p0 = n0 & 4095;
    const float* xb = x + (size_t)b * CCH * HW + p0;
    float* ob = out + (size_t)b * CCH * HW + p0;
    int lane = tid & 63, wv = tid >> 6;
    for (int i = 0; i < 64; i++) {
        int c = i * 4 + wv;
        ob[(size_t)c * HW + lane] = xb[(size_t)c * HW + lane] + sc * moe[c][lane];
    }
}

// ---------------- launch ----------------------------------------------------
extern "C" void kernel_launch(void* const* d_in, const int* in_sizes, int n_in,
                              void* d_out, int out_size, void* d_ws, size_t ws_size,
                              hipStream_t stream)
{
    const float* x     = (const float*)d_in[0];
    const float* Wr    = (const float*)d_in[1];
    const float* br    = (const float*)d_in[2];
    const float* W1    = (const float*)d_in[3];
    const float* b1    = (const float*)d_in[4];
    const float* W2    = (const float*)d_in[5];
    const float* b2    = (const float*)d_in[6];
    const float* scale = (const float*)d_in[7];
    float* out = (float*)d_out;

    char* ws = (char*)d_ws;
    __hip_bfloat16* tokens = (__hip_bfloat16*)(ws);                 // 33,554,432 B
    __hip_bfloat16* w1t    = (__hip_bfloat16*)(ws + 33554432);      //  2,097,152 B
    __hip_bfloat16* w2t    = (__hip_bfloat16*)(ws + 35651584);      //  2,097,152 B
    __hip_bfloat16* ybuf   = (__hip_bfloat16*)(ws + 37748736);      // 67,108,864 B
    int*    assign_tok = (int*)   (ws + 104857600);                 //    524,288 B
    float*  assign_w   = (float*) (ws + 105381888);                 //    524,288 B
    int2*   tok_slots  = (int2*)  (ws + 105906176);                 //    524,288 B
    int*    pair       = (int*)   (ws + 106430464);                 //    262,144 B
    float2* wts        = (float2*)(ws + 106692608);                 //    524,288 B
    int*    meta       = (int*)   (ws + 107216896);                 //        256 B

    hipMemsetAsync(meta, 0, 64, stream);  // counts + cursors
    k_transpose_cast<<<256, 256, 0, stream>>>(W1, w1t, 256, 512);
    k_transpose_cast<<<256, 256, 0, stream>>>(W2, w2t, 512, 256);
    k_router<<<1024, 256, 0, stream>>>(x, Wr, br, tokens, pair, wts, meta);
    k_scan<<<1, 64, 0, stream>>>(meta);
    k_scatter<<<256, 256, 0, stream>>>(pair, wts, meta, assign_tok, assign_w, tok_slots);
    k_expert<<<NE * MAXT, 512, 0, stream>>>(tokens, w1t, w2t, b1, b2, meta,
                                            assign_tok, assign_w, ybuf);
    k_combine<<<1024, 256, 0, stream>>>(x, ybuf, tok_slots, scale, out);
}